// Round 1
// baseline (303.927 us; speedup 1.0000x reference)
//
#include <hip/hip_runtime.h>

#define HW_SHIFT 18               // H*W = 512*512 = 2^18
#define HW (1 << HW_SHIFT)
#define NC 6
#define NIC 3
#define EPS 1e-5f

__global__ __launch_bounds__(256) void aff_softmax_kernel(
    const float* __restrict__ x,
    const float* __restrict__ w1, const float* __restrict__ b1,
    const float* __restrict__ g1, const float* __restrict__ be1,
    const float* __restrict__ m1, const float* __restrict__ v1,
    const float* __restrict__ w2, const float* __restrict__ b2,
    const float* __restrict__ g2, const float* __restrict__ be2,
    const float* __restrict__ m2, const float* __restrict__ v2,
    float* __restrict__ out)
{
    const int g = blockIdx.x * blockDim.x + threadIdx.x;

    // ---- Fold BN1 into conv1, BN2 into conv2 (all uniform scalars; compiler
    // keeps these as wave-uniform values; cheap vs. memory floor). ----
    float W1f[NIC][NC], B1f[NIC];
#pragma unroll
    for (int o = 0; o < NIC; ++o) {
        const float inv = g1[o] * rsqrtf(v1[o] + EPS);
        B1f[o] = b1[o] * inv + (be1[o] - m1[o] * inv);
#pragma unroll
        for (int c = 0; c < NC; ++c) W1f[o][c] = w1[o * NC + c] * inv;
    }
    float W2f[NC][NIC], B2f[NC];
#pragma unroll
    for (int o = 0; o < NC; ++o) {
        const float inv = g2[o] * rsqrtf(v2[o] + EPS);
        B2f[o] = b2[o] * inv + (be2[o] - m2[o] * inv);
#pragma unroll
        for (int c = 0; c < NIC; ++c) W2f[o][c] = w2[o * NIC + c] * inv;
    }

    // ---- 4 pixels per thread, float4 per channel plane ----
    const long p  = (long)g << 2;               // first pixel index (global over B*H*W)
    const int  b  = (int)(p >> HW_SHIFT);       // batch
    const int  hw = (int)(p & (HW - 1));        // offset within plane
    const float* xb = x + ((long)b * NC << HW_SHIFT) + hw;

    float4 xv[NC];
#pragma unroll
    for (int c = 0; c < NC; ++c)
        xv[c] = *(const float4*)(xb + ((long)c << HW_SHIFT));

    float4 res;
    float* resf = (float*)&res;
#pragma unroll
    for (int i = 0; i < 4; ++i) {
        float xc[NC];
#pragma unroll
        for (int c = 0; c < NC; ++c) xc[c] = ((const float*)&xv[c])[i];

        // conv1 + BN1 + ReLU
        float h1[NIC];
#pragma unroll
        for (int o = 0; o < NIC; ++o) {
            float a = B1f[o];
#pragma unroll
            for (int c = 0; c < NC; ++c) a = fmaf(W1f[o][c], xc[c], a);
            h1[o] = fmaxf(a, 0.0f);
        }

        // conv2 + BN2
        float h2[NC];
        float mx = -3.4e38f;
#pragma unroll
        for (int o = 0; o < NC; ++o) {
            float a = B2f[o];
#pragma unroll
            for (int c = 0; c < NIC; ++c) a = fmaf(W2f[o][c], h1[c], a);
            h2[o] = a;
            mx = fmaxf(mx, a);
        }

        // softmax over channels fused with weighted sum over channels
        float sum = 0.0f, acc = 0.0f;
#pragma unroll
        for (int o = 0; o < NC; ++o) {
            const float e = __expf(h2[o] - mx);
            sum += e;
            acc = fmaf(e, xc[o], acc);
        }
        resf[i] = acc / sum;
    }

    *(float4*)(out + p) = res;
}

extern "C" void kernel_launch(void* const* d_in, const int* in_sizes, int n_in,
                              void* d_out, int out_size, void* d_ws, size_t ws_size,
                              hipStream_t stream) {
    const float* x   = (const float*)d_in[0];
    const float* w1  = (const float*)d_in[1];
    const float* b1  = (const float*)d_in[2];
    const float* g1  = (const float*)d_in[3];
    const float* be1 = (const float*)d_in[4];
    const float* m1  = (const float*)d_in[5];
    const float* v1  = (const float*)d_in[6];
    const float* w2  = (const float*)d_in[7];
    const float* b2  = (const float*)d_in[8];
    const float* g2  = (const float*)d_in[9];
    const float* be2 = (const float*)d_in[10];
    const float* m2  = (const float*)d_in[11];
    const float* v2  = (const float*)d_in[12];
    float* out = (float*)d_out;

    // out_size = 32*512*512 = 8,388,608 pixels; 4 pixels/thread
    const int threads = 256;
    const int total4  = out_size / 4;               // 2,097,152
    const int blocks  = (total4 + threads - 1) / threads;  // 8192

    aff_softmax_kernel<<<blocks, threads, 0, stream>>>(
        x, w1, b1, g1, be1, m1, v1, w2, b2, g2, be2, m2, v2, out);
}